// Round 14
// baseline (151.937 us; speedup 1.0000x reference)
//
#include <hip/hip_runtime.h>
#include <cfloat>
#include <cmath>

#define MEM_DIM 2000
#define FEA     256
#define LAMBDA  0.0025f
#define HS_EPS  1e-12f

typedef unsigned short u16;
typedef unsigned int   u32;
typedef _Float16 f16x8  __attribute__((ext_vector_type(8)));
typedef float    f32x16 __attribute__((ext_vector_type(16)));

static const int Y_ELEMS = 16 * 256 * 1024;   // y output elements

// workspace layout (float offsets), total 783616 floats < 3.0 MB:
//   [0 .. 524287]      : wsp u16[2][2048][256] (2 MB) while scores runs
//   [524288 .. 786431] : zp [16][16384] (1 MB) until k_zsum consumes it
//   AFTER those phases the regions are reused:
#define WS_Z     0        //  Z    [16384] full row sums
#define WS_DD    16384    //  dD   [16384] L1 denominators (atomic, survivor-only)
#define WS_CNTH  32768    //  cnth [1024] hw-chunk counters (u32, pad 2048)
#define WS_CNTM  34816    //  cntm [2000] m-panel counters (u32, pad 2048)
#define WS_BKTH  36864    //  bkth [1024][224] uint2 -> ends 495616
#define WS_BKTM  495616   //  bktm [2000][72]  uint2 -> ends 783616 (annexes dead zp)
#define WS_ZP    524288   //  zp (dead after k_zsum)
#define CAP_H 224
#define CAP_M 72

// ---------------------------------------------------------------------------
// Kernel A+B merged: split x -> xs planes; split W -> wsp planes.
// ---------------------------------------------------------------------------
__global__ __launch_bounds__(256) void k_split(const float* __restrict__ x,
                                               const float* __restrict__ W,
                                               u16* __restrict__ xs,
                                               u16* __restrict__ wsp) {
    __shared__ float tl[32][33];
    const int blk = blockIdx.x;
    if (blk < 4096) {
        const int b   = blk >> 8;
        const int ct  = (blk >> 5) & 7;
        const int ht  = blk & 31;
        const int tx  = threadIdx.x & 31, ty = threadIdx.x >> 5;
#pragma unroll
        for (int i = 0; i < 4; ++i)
            tl[ty + 8 * i][tx] =
                x[(((b << 8) + (ct << 5) + ty + (i << 3)) << 10) + (ht << 5) + tx];
        __syncthreads();
#pragma unroll
        for (int i = 0; i < 4; ++i) {
            float v = tl[tx][ty + 8 * i];
            _Float16 a  = (_Float16)v;
            _Float16 bq = (_Float16)((v - (float)a) * 256.0f);
            const int hw = (ht << 5) + ty + (i << 3);
            const int c  = (ct << 5) + tx;
            const size_t o = (((size_t)(b << 10) + hw) << 8) + c;
            xs[o]           = *(u16*)&a;
            xs[4194304 + o] = *(u16*)&bq;
        }
    } else {
        const int m = blk - 4096;             // 0..2047
        const int c = threadIdx.x;
        float v = (m < MEM_DIM) ? W[(m << 8) + c] : 0.f;
        _Float16 a  = (_Float16)v;
        _Float16 bq = (_Float16)((v - (float)a) * 256.0f);
        wsp[(m << 8) + c]          = *(u16*)&a;
        wsp[524288 + (m << 8) + c] = *(u16*)&bq;
    }
}

// ---------------------------------------------------------------------------
// Kernel 1: z = x.W^T via mfma_f32_32x32x16_f16, 2-split (3 passes, dual acc).
// 512 threads = 8 waves of 64x32 (was 4 waves of 64x64): per-thread acc
// halves to 64 AGPR -> total regs ~<=128 -> 4 waves/SIMD (2x occupancy).
// Same 128x128 block tile, LDS layout, swizzle, K-order: E bit-identical.
// zp partial-sum grouping changes (4x32-m strips) -> Z shifts ~1 ulp.
// ---------------------------------------------------------------------------
__global__ __launch_bounds__(512) void k_scores_mfma(
    const u16* __restrict__ xs, const u16* __restrict__ wsp,
    float* __restrict__ S, float* __restrict__ zp) {
    __shared__ u16 lds[32768];   // 64 KB = 2 x 32 KB buffers
    const int t    = threadIdx.x;
    const int lane = t & 63;
    const int w    = t >> 6;          // 0..7
    const int wr   = w >> 2;          // 0..1 : row half (64 rows)
    const int wc   = w & 3;           // 0..3 : m strip (32 m)
    const int lr   = lane & 31, lg = lane >> 5;

    const int bx  = blockIdx.x;
    const int wg  = ((bx & 7) << 8) | (bx >> 3);   // XCD swizzle (2048 = 8*256)
    const int m0t = wg & 15;
    const int rt  = wg >> 4;
    const int m0  = m0t << 7;
    const int b   = rt >> 3;
    const int hw0 = (rt & 7) << 7;

    // staging: 4 issues x 512 thr x 16 B = 32 KB/buffer. slot s=(i<<9)+t:
    // tile = i, row r = t>>2, phys chunk t&3 holds logical (t&3)^((r>>1)&3).
    const u16* gsrc[4];
#pragma unroll
    for (int i = 0; i < 4; ++i) {
        const int r  = t >> 2;
        const int cl = (t & 3) ^ ((r >> 1) & 3);
        if (i < 2)
            gsrc[i] = xs + i * 4194304 + (((b << 10) + hw0 + r) << 8) + (cl << 3);
        else
            gsrc[i] = wsp + ((i - 2) << 19) + ((m0 + r) << 8) + (cl << 3);
    }

    f32x16 acc1[2], acc2[2];
#pragma unroll
    for (int i = 0; i < 2; ++i)
#pragma unroll
        for (int e = 0; e < 16; ++e) { acc1[i][e] = 0.f; acc2[i][e] = 0.f; }

    #define STAGE(kt, bufb)                                                          \
        {                                                                            \
            _Pragma("unroll")                                                        \
            for (int i = 0; i < 4; ++i) {                                            \
                const int s = (i << 9) + t;                                          \
                __builtin_amdgcn_global_load_lds(                                    \
                    (const __attribute__((address_space(1))) unsigned int*)(gsrc[i] + ((kt) << 5)), \
                    (__attribute__((address_space(3))) unsigned int*)&lds[(bufb) + (s << 3)],       \
                    16, 0, 0);                                                       \
            }                                                                        \
        }

    #define COMPUTE(bufb)                                                            \
        {                                                                            \
            _Pragma("unroll")                                                        \
            for (int ks = 0; ks < 2; ++ks) {                                         \
                f16x8 a0[2], a1[2], b0, b1;                                          \
                _Pragma("unroll")                                                    \
                for (int ri = 0; ri < 2; ++ri) {                                     \
                    const int R  = (wr << 6) + (ri << 5) + lr;                       \
                    const int pc = ((ks << 1) + lg) ^ ((R >> 1) & 3);                \
                    a0[ri] = *(const f16x8*)&lds[(bufb) +        (R << 5) + (pc << 3)]; \
                    a1[ri] = *(const f16x8*)&lds[(bufb) + 4096 + (R << 5) + (pc << 3)]; \
                }                                                                    \
                {                                                                    \
                    const int M  = (wc << 5) + lr;                                   \
                    const int pc = ((ks << 1) + lg) ^ ((M >> 1) & 3);                \
                    b0 = *(const f16x8*)&lds[(bufb) +  8192 + (M << 5) + (pc << 3)]; \
                    b1 = *(const f16x8*)&lds[(bufb) + 12288 + (M << 5) + (pc << 3)]; \
                }                                                                    \
                _Pragma("unroll")                                                    \
                for (int ri = 0; ri < 2; ++ri) {                                     \
                    acc2[ri] = __builtin_amdgcn_mfma_f32_32x32x16_f16(a0[ri], b1, acc2[ri], 0, 0, 0); \
                    acc2[ri] = __builtin_amdgcn_mfma_f32_32x32x16_f16(a1[ri], b0, acc2[ri], 0, 0, 0); \
                    acc1[ri] = __builtin_amdgcn_mfma_f32_32x32x16_f16(a0[ri], b0, acc1[ri], 0, 0, 0); \
                }                                                                    \
            }                                                                        \
        }

    STAGE(0, 0);
    __syncthreads();
#pragma unroll
    for (int kt = 0; kt < 8; ++kt) {
        if (kt < 7) STAGE(kt + 1, ((kt + 1) & 1) << 14);
        COMPUTE((kt & 1) << 14);
        __syncthreads();
    }
    #undef STAGE
    #undef COMPUTE

    float* zf = (float*)lds;          // 512 floats: [wc][row 0..127]

    const int m = m0 + (wc << 5) + lr;
    const bool valid = (m < MEM_DIM);
#pragma unroll
    for (int ri = 0; ri < 2; ++ri) {
        float e[16];
        float rs[16];
#pragma unroll
        for (int q = 0; q < 16; ++q) {
            float z = acc1[ri][q] + acc2[ri][q] * 0.00390625f;
            e[q] = valid ? expf(z) : 0.f;
            rs[q] = e[q];
        }
        if (valid) {
            const size_t pb = ((size_t)(b * MEM_DIM + m) << 10) + hw0
                            + (wr << 6) + (ri << 5) + (lg << 2);
#pragma unroll
            for (int q4 = 0; q4 < 4; ++q4) {
                float4 v = {e[4 * q4], e[4 * q4 + 1], e[4 * q4 + 2], e[4 * q4 + 3]};
                *(float4*)&S[pb + (q4 << 3)] = v;
            }
        }
#pragma unroll
        for (int q = 0; q < 16; ++q) {
            float v = rs[q];
            v += __shfl_xor(v, 1);
            v += __shfl_xor(v, 2);
            v += __shfl_xor(v, 4);
            v += __shfl_xor(v, 8);
            v += __shfl_xor(v, 16);
            rs[q] = v;
        }
        if (lr == 0) {
#pragma unroll
            for (int q = 0; q < 16; ++q) {
                const int row = (wr << 6) + (ri << 5) + (q & 3) + ((q >> 2) << 3) + (lg << 2);
                zf[(wc << 7) + row] = rs[q];
            }
        }
    }
    __syncthreads();
    if (t < 128)
        zp[m0t * 16384 + (b << 10) + hw0 + t] =
            zf[t] + zf[128 + t] + zf[256 + t] + zf[384 + t];
}

// ---------------------------------------------------------------------------
// Kernel 2: Z = sum of 16 zp planes; zero dD and both counter arrays.
// ---------------------------------------------------------------------------
__global__ __launch_bounds__(256) void k_zsum(const float* __restrict__ zp,
                                              float* __restrict__ Z,
                                              float* __restrict__ dD,
                                              u32* __restrict__ cnth,
                                              u32* __restrict__ cntm) {
    const int i = blockIdx.x * 256 + threadIdx.x;   // 16384
    float z = 0.f;
#pragma unroll
    for (int mt = 0; mt < 16; ++mt) z += zp[mt * 16384 + i];
    Z[i] = z;
    dD[i] = 0.f;
    if (i < 1024) cnth[i] = 0;
    if (i < 2048) cntm[i] = 0;
}

// ---------------------------------------------------------------------------
// Kernel 3: single dense E-consumer (round-13-proven). Survivors (d>0):
// survivor-only dD atomics, global-atomic bkth append, LDS-staged bktm.
// ---------------------------------------------------------------------------
__global__ __launch_bounds__(256) void k_pvD(const float* __restrict__ att,
                                             const float* __restrict__ Z,
                                             float* __restrict__ dD,
                                             u32* __restrict__ cnth,
                                             u32* __restrict__ cntm,
                                             uint2* __restrict__ bkth,
                                             uint2* __restrict__ bktm) {
    __shared__ uint2 lbkt[CAP_M];
    __shared__ u32 lcnt;
    const int blk = blockIdx.x;          // 2000 = 16 b x 125 panel-groups
    const int b   = blk / 125;
    const int mg  = blk % 125;
    const int t   = threadIdx.x;
    const int hw  = t << 2;
    if (t == 0) lcnt = 0;
    __syncthreads();

    float4 Z4 = *(const float4*)&Z[(b << 10) + hw];
    const float4 rZ = {1.f / Z4.x, 1.f / Z4.y, 1.f / Z4.z, 1.f / Z4.w};
    const size_t pb = ((size_t)(b * MEM_DIM + mg * 16) << 10) + hw;

#pragma unroll
    for (int i = 0; i < 16; ++i) {
        const int m = mg * 16 + i;
        float4 e = *(const float4*)&att[pb + ((size_t)i << 10)];
        float aa[4] = {e.x * rZ.x, e.y * rZ.y, e.z * rZ.z, e.w * rZ.w};
#pragma unroll
        for (int c = 0; c < 4; ++c) {
            const float d = aa[c] - LAMBDA;
            if (d > 0.f) {
                const float sv = d * aa[c] / (d + HS_EPS);   // == fmax(d,0)*a/(|d|+eps)
                const int hwc = hw + c;
                atomicAdd(&dD[(b << 10) + hwc], sv);
                const int ch = (b << 6) + (hwc >> 4);
                u32 ih = atomicAdd(&cnth[ch], 1u);
                if (ih < (u32)CAP_H)
                    bkth[ch * CAP_H + ih] =
                        make_uint2((u32)m | ((u32)(hwc & 15) << 16), __float_as_uint(sv));
                u32 im = atomicAdd(&lcnt, 1u);
                if (im < (u32)CAP_M)
                    lbkt[im] = make_uint2((u32)hwc | ((u32)(m & 15) << 16),
                                          __float_as_uint(sv));
            }
        }
    }
    __syncthreads();
    const u32 n = lcnt;
    if (t == 0) cntm[blk] = n;
    if (t < n && t < (u32)CAP_M) bktm[blk * CAP_M + t] = lbkt[t];
}

// ---------------------------------------------------------------------------
// Kernel 4: att production, panel-contiguous: zero-fill + survivor scatter.
// Overflow fallback: dense recompute from still-intact E of this panel.
// ---------------------------------------------------------------------------
__global__ __launch_bounds__(256) void k_att(float* __restrict__ att,
                                             const float* __restrict__ Z,
                                             const float* __restrict__ dD,
                                             const u32* __restrict__ cntm,
                                             const uint2* __restrict__ bktm) {
    const int blk = blockIdx.x;          // 2000
    const int b   = blk / 125;
    const int mg  = blk % 125;
    const int t   = threadIdx.x;
    const size_t pb = (size_t)(b * MEM_DIM + mg * 16) << 10;
    const u32 n_raw = cntm[blk];

    if (n_raw <= (u32)CAP_M) {
        float4* p4 = (float4*)&att[pb];
        const float4 z4 = {0.f, 0.f, 0.f, 0.f};
        for (int i = t; i < 4096; i += 256) p4[i] = z4;
        __syncthreads();
        const int n = (int)n_raw;
        for (int i = t; i < n; i += 256) {
            uint2 e = bktm[blk * CAP_M + i];
            const int hw = e.x & 0xFFFF;
            const int mi = e.x >> 16;
            const float rd = 1.f / fmaxf(dD[(b << 10) + hw], HS_EPS);
            att[pb + ((size_t)mi << 10) + hw] = __uint_as_float(e.y) * rd;
        }
    } else {
#pragma unroll
        for (int c = 0; c < 4; ++c) {
            const int hw = t + (c << 8);
            const float rz = 1.f / Z[(b << 10) + hw];
            const float rd = 1.f / fmaxf(dD[(b << 10) + hw], HS_EPS);
            for (int mi = 0; mi < 16; ++mi) {
                float e = att[pb + ((size_t)mi << 10) + hw];
                float a = e * rz, d = a - LAMBDA;
                att[pb + ((size_t)mi << 10) + hw] =
                    fmaxf(d, 0.f) * a / (fabsf(d) + HS_EPS) * rd;
            }
        }
    }
}

// ---------------------------------------------------------------------------
// Kernel 5: y from hw-chunk survivor buckets (rD at consumption).
// Overflow fallback: dense scan of FINAL att (k_att ran before).
// ---------------------------------------------------------------------------
__global__ __launch_bounds__(256) void k_y(const float* __restrict__ W,
                                           const u32* __restrict__ cnth,
                                           const uint2* __restrict__ bkth,
                                           const float* __restrict__ dD,
                                           const float* __restrict__ att,
                                           float* __restrict__ y) {
    __shared__ float ylds[16][257];
    __shared__ float rDsh[16];
    const int ch  = blockIdx.x;           // 1024
    const int b   = ch >> 6;
    const int hw0 = (ch & 63) << 4;
    const int t   = threadIdx.x;

    for (int i = t; i < 16 * 257; i += 256) ((float*)ylds)[i] = 0.f;
    if (t < 16) rDsh[t] = 1.f / fmaxf(dD[(b << 10) + hw0 + t], HS_EPS);
    __syncthreads();

    const u32 n_raw = cnth[ch];
    if (n_raw <= (u32)CAP_H) {
        const int n = (int)n_raw;
        for (int i = 0; i < n; ++i) {
            uint2 e = bkth[ch * CAP_H + i];
            const int m  = e.x & 0xFFFF;
            const int r4 = e.x >> 16;
            const float v = __uint_as_float(e.y) * rDsh[r4];
            ylds[r4][t] += v * W[(m << 8) + t];
        }
    } else {
        const int r  = t & 15;
        const int mo = t >> 4;
        for (int m = mo; m < MEM_DIM; m += 16) {
            float a = att[((size_t)(b * MEM_DIM + m) << 10) + hw0 + r];
            if (a != 0.f) {
                for (int c = 0; c < 256; ++c)
                    atomicAdd(&ylds[r][c], a * W[(m << 8) + c]);
            }
        }
    }
    __syncthreads();

#pragma unroll
    for (int it = 0; it < 16; ++it) {
        const int cc = (it << 4) + (t >> 4);
        const int r  = t & 15;
        y[(((b << 8) + cc) << 10) + hw0 + r] = ylds[r][cc];
    }
}

// ---------------------------------------------------------------------------
extern "C" void kernel_launch(void* const* d_in, const int* in_sizes, int n_in,
                              void* d_out, int out_size, void* d_ws, size_t ws_size,
                              hipStream_t stream) {
    const float* x = (const float*)d_in[0];
    const float* W = (const float*)d_in[1];
    float* out = (float*)d_out;
    float* y   = out;
    float* att = out + (size_t)Y_ELEMS;
    float* wsf = (float*)d_ws;
    u16*   wsp  = (u16*)d_ws;                 // 2 MB, dead after k_scores_mfma
    float* Z    = wsf + WS_Z;                 // reuses wsp region
    float* dD   = wsf + WS_DD;                // reuses wsp region
    u32*   cnth = (u32*)(wsf + WS_CNTH);      // reuses wsp region
    u32*   cntm = (u32*)(wsf + WS_CNTM);      // reuses wsp region
    uint2* bkth = (uint2*)(wsf + WS_BKTH);    // reuses wsp region
    uint2* bktm = (uint2*)(wsf + WS_BKTM);    // reuses wsp tail + dead zp
    float* zp   = wsf + WS_ZP;                // dead after k_zsum
    u16*   xs   = (u16*)y;                    // 16.8 MB staging in y region
                                              // (consumed before k_y writes y)

    k_split      <<<6144, 256, 0, stream>>>(x, W, xs, wsp);
    k_scores_mfma<<<2048, 512, 0, stream>>>(xs, wsp, att, zp);
    k_zsum       <<<64,   256, 0, stream>>>(zp, Z, dD, cnth, cntm);
    k_pvD        <<<2000, 256, 0, stream>>>(att, Z, dD, cnth, cntm, bkth, bktm);
    k_att        <<<2000, 256, 0, stream>>>(att, Z, dD, cntm, bktm);
    k_y          <<<1024, 256, 0, stream>>>(W, cnth, bkth, dD, att, y);
}

// Round 16
// 145.410 us; speedup vs baseline: 1.0449x; 1.0449x over previous
//
#include <hip/hip_runtime.h>
#include <cfloat>
#include <cmath>

#define MEM_DIM 2000
#define FEA     256
#define LAMBDA  0.0025f
#define HS_EPS  1e-12f

typedef unsigned short u16;
typedef unsigned int   u32;
typedef _Float16 f16x8  __attribute__((ext_vector_type(8)));
typedef float    f32x16 __attribute__((ext_vector_type(16)));

static const int Y_ELEMS = 16 * 256 * 1024;   // y output elements

// workspace layout (float offsets), total 783616 floats < 3.0 MB:
//   [0 .. 524287]      : wsp u16[2][2048][256] (2 MB) while scores runs
//   [524288 .. 786431] : zp [16][16384] (1 MB) until k_zsum consumes it
//   AFTER those phases the regions are reused:
#define WS_Z     0        //  Z    [16384] full row sums
#define WS_DD    16384    //  dD   [16384] L1 denominators (atomic, survivor-only)
#define WS_CNTH  32768    //  cnth [1024] hw-chunk counters (u32, pad 2048)
#define WS_CNTM  34816    //  cntm [2000] m-panel counters (u32, pad 2048)
#define WS_BKTH  36864    //  bkth [1024][224] uint2 -> ends 495616
#define WS_BKTM  495616   //  bktm [2000][72]  uint2 -> ends 783616 (annexes dead zp)
#define WS_ZP    524288   //  zp (dead after k_zsum)
#define CAP_H 224
#define CAP_M 72

// ---------------------------------------------------------------------------
// Kernel A+B merged: split x -> xs planes; split W -> wsp planes.
// ---------------------------------------------------------------------------
__global__ __launch_bounds__(256) void k_split(const float* __restrict__ x,
                                               const float* __restrict__ W,
                                               u16* __restrict__ xs,
                                               u16* __restrict__ wsp) {
    __shared__ float tl[32][33];
    const int blk = blockIdx.x;
    if (blk < 4096) {
        const int b   = blk >> 8;
        const int ct  = (blk >> 5) & 7;
        const int ht  = blk & 31;
        const int tx  = threadIdx.x & 31, ty = threadIdx.x >> 5;
#pragma unroll
        for (int i = 0; i < 4; ++i)
            tl[ty + 8 * i][tx] =
                x[(((b << 8) + (ct << 5) + ty + (i << 3)) << 10) + (ht << 5) + tx];
        __syncthreads();
#pragma unroll
        for (int i = 0; i < 4; ++i) {
            float v = tl[tx][ty + 8 * i];
            _Float16 a  = (_Float16)v;
            _Float16 bq = (_Float16)((v - (float)a) * 256.0f);
            const int hw = (ht << 5) + ty + (i << 3);
            const int c  = (ct << 5) + tx;
            const size_t o = (((size_t)(b << 10) + hw) << 8) + c;
            xs[o]           = *(u16*)&a;
            xs[4194304 + o] = *(u16*)&bq;
        }
    } else {
        const int m = blk - 4096;             // 0..2047
        const int c = threadIdx.x;
        float v = (m < MEM_DIM) ? W[(m << 8) + c] : 0.f;
        _Float16 a  = (_Float16)v;
        _Float16 bq = (_Float16)((v - (float)a) * 256.0f);
        wsp[(m << 8) + c]          = *(u16*)&a;
        wsp[524288 + (m << 8) + c] = *(u16*)&bq;
    }
}

// ---------------------------------------------------------------------------
// Kernel 1: z = x.W^T via mfma_f32_32x32x16_f16, 2-split (3 passes, dual acc).
// EXACT round-11/13 proven version (bit-identical E): 64 KB dbuf, 8-load
// STAGE, 2-phase __syncthreads pipeline, 2-way chunk swizzle, direct float4
// E-store epilogue. (r15's hand-rolled counted-vmcnt barriers raced on
// replay — reverted to the compiler-managed barrier structure.)
// ---------------------------------------------------------------------------
__global__ __launch_bounds__(256) void k_scores_mfma(
    const u16* __restrict__ xs, const u16* __restrict__ wsp,
    float* __restrict__ S, float* __restrict__ zp) {
    __shared__ u16 lds[32768];   // 64 KB = 2 x 32 KB buffers
    const int t    = threadIdx.x;
    const int lane = t & 63;
    const int w    = t >> 6;
    const int wr   = w >> 1, wc = w & 1;
    const int lr   = lane & 31, lg = lane >> 5;

    const int bx  = blockIdx.x;
    const int wg  = ((bx & 7) << 8) | (bx >> 3);   // XCD swizzle (2048 = 8*256)
    const int m0t = wg & 15;
    const int rt  = wg >> 4;
    const int m0  = m0t << 7;
    const int b   = rt >> 3;
    const int hw0 = (rt & 7) << 7;

    const u16* gsrc[8];
#pragma unroll
    for (int i = 0; i < 8; ++i) {
        const int s = (i << 8) + t;
        const int tile = s >> 9;
        const int u = s & 511;
        const int r = u >> 2;
        const int cl = (u & 3) ^ ((r >> 1) & 3);
        if (tile < 2)
            gsrc[i] = xs + tile * 4194304 + (((b << 10) + hw0 + r) << 8) + (cl << 3);
        else
            gsrc[i] = wsp + ((tile - 2) << 19) + ((m0 + r) << 8) + (cl << 3);
    }

    f32x16 acc1[2][2], acc2[2][2];
#pragma unroll
    for (int i = 0; i < 2; ++i)
#pragma unroll
        for (int j = 0; j < 2; ++j)
#pragma unroll
            for (int e = 0; e < 16; ++e) { acc1[i][j][e] = 0.f; acc2[i][j][e] = 0.f; }

    #define STAGE(kt, bufb)                                                          \
        {                                                                            \
            _Pragma("unroll")                                                        \
            for (int i = 0; i < 8; ++i) {                                            \
                const int s = (i << 8) + t;                                          \
                __builtin_amdgcn_global_load_lds(                                    \
                    (const __attribute__((address_space(1))) unsigned int*)(gsrc[i] + ((kt) << 5)), \
                    (__attribute__((address_space(3))) unsigned int*)&lds[(bufb) + (s << 3)],       \
                    16, 0, 0);                                                       \
            }                                                                        \
        }

    #define COMPUTE(bufb)                                                            \
        {                                                                            \
            _Pragma("unroll")                                                        \
            for (int ks = 0; ks < 2; ++ks) {                                         \
                f16x8 a0[2], a1[2], b0[2], b1[2];                                    \
                _Pragma("unroll")                                                    \
                for (int ri = 0; ri < 2; ++ri) {                                     \
                    const int R  = (wr << 6) + (ri << 5) + lr;                       \
                    const int pc = ((ks << 1) + lg) ^ ((R >> 1) & 3);                \
                    a0[ri] = *(const f16x8*)&lds[(bufb) +        (R << 5) + (pc << 3)]; \
                    a1[ri] = *(const f16x8*)&lds[(bufb) + 4096 + (R << 5) + (pc << 3)]; \
                }                                                                    \
                _Pragma("unroll")                                                    \
                for (int mi = 0; mi < 2; ++mi) {                                     \
                    const int M  = (wc << 6) + (mi << 5) + lr;                       \
                    const int pc = ((ks << 1) + lg) ^ ((M >> 1) & 3);                \
                    b0[mi] = *(const f16x8*)&lds[(bufb) +  8192 + (M << 5) + (pc << 3)]; \
                    b1[mi] = *(const f16x8*)&lds[(bufb) + 12288 + (M << 5) + (pc << 3)]; \
                }                                                                    \
                _Pragma("unroll")                                                    \
                for (int ri = 0; ri < 2; ++ri)                                       \
                    _Pragma("unroll")                                                \
                    for (int mi = 0; mi < 2; ++mi) {                                 \
                        acc2[ri][mi] = __builtin_amdgcn_mfma_f32_32x32x16_f16(a0[ri], b1[mi], acc2[ri][mi], 0, 0, 0); \
                        acc2[ri][mi] = __builtin_amdgcn_mfma_f32_32x32x16_f16(a1[ri], b0[mi], acc2[ri][mi], 0, 0, 0); \
                        acc1[ri][mi] = __builtin_amdgcn_mfma_f32_32x32x16_f16(a0[ri], b0[mi], acc1[ri][mi], 0, 0, 0); \
                    }                                                                \
            }                                                                        \
        }

    STAGE(0, 0);
    __syncthreads();
#pragma unroll
    for (int kt = 0; kt < 8; ++kt) {
        if (kt < 7) STAGE(kt + 1, ((kt + 1) & 1) << 14);
        COMPUTE((kt & 1) << 14);
        __syncthreads();
    }
    #undef STAGE
    #undef COMPUTE

    float* zf = (float*)lds;

    float rs[2][16];
#pragma unroll
    for (int ri = 0; ri < 2; ++ri)
#pragma unroll
        for (int q = 0; q < 16; ++q) rs[ri][q] = 0.f;

#pragma unroll
    for (int ri = 0; ri < 2; ++ri)
#pragma unroll
        for (int mi = 0; mi < 2; ++mi) {
            const int m = m0 + (wc << 6) + (mi << 5) + lr;
            const bool valid = (m < MEM_DIM);
            float e[16];
#pragma unroll
            for (int q = 0; q < 16; ++q) {
                float z = acc1[ri][mi][q] + acc2[ri][mi][q] * 0.00390625f;
                e[q] = valid ? expf(z) : 0.f;
                rs[ri][q] += e[q];
            }
            if (valid) {
                const size_t pb = ((size_t)(b * MEM_DIM + m) << 10) + hw0
                                + (wr << 6) + (ri << 5) + (lg << 2);
#pragma unroll
                for (int q4 = 0; q4 < 4; ++q4) {
                    float4 v = {e[4 * q4], e[4 * q4 + 1], e[4 * q4 + 2], e[4 * q4 + 3]};
                    *(float4*)&S[pb + (q4 << 3)] = v;
                }
            }
        }

#pragma unroll
    for (int ri = 0; ri < 2; ++ri)
#pragma unroll
        for (int q = 0; q < 16; ++q) {
            float v = rs[ri][q];
            v += __shfl_xor(v, 1);
            v += __shfl_xor(v, 2);
            v += __shfl_xor(v, 4);
            v += __shfl_xor(v, 8);
            v += __shfl_xor(v, 16);
            rs[ri][q] = v;
        }
    if (lr == 0) {
#pragma unroll
        for (int ri = 0; ri < 2; ++ri)
#pragma unroll
            for (int q = 0; q < 16; ++q) {
                const int row = (wr << 6) + (ri << 5) + (q & 3) + ((q >> 2) << 3) + (lg << 2);
                zf[(wc << 7) + row] = rs[ri][q];
            }
    }
    __syncthreads();
    if (t < 128)
        zp[m0t * 16384 + (b << 10) + hw0 + t] = zf[t] + zf[128 + t];
}

// ---------------------------------------------------------------------------
// Kernel 2: Z = sum of 16 zp planes; zero dD and both counter arrays.
// ---------------------------------------------------------------------------
__global__ __launch_bounds__(256) void k_zsum(const float* __restrict__ zp,
                                              float* __restrict__ Z,
                                              float* __restrict__ dD,
                                              u32* __restrict__ cnth,
                                              u32* __restrict__ cntm) {
    const int i = blockIdx.x * 256 + threadIdx.x;   // 16384
    float z = 0.f;
#pragma unroll
    for (int mt = 0; mt < 16; ++mt) z += zp[mt * 16384 + i];
    Z[i] = z;
    dD[i] = 0.f;
    if (i < 1024) cnth[i] = 0;
    if (i < 2048) cntm[i] = 0;
}

// ---------------------------------------------------------------------------
// Kernel 3: single dense E-consumer (round-13-proven). Survivors (d>0):
// survivor-only dD atomics, global-atomic bkth append, LDS-staged bktm.
// ---------------------------------------------------------------------------
__global__ __launch_bounds__(256) void k_pvD(const float* __restrict__ att,
                                             const float* __restrict__ Z,
                                             float* __restrict__ dD,
                                             u32* __restrict__ cnth,
                                             u32* __restrict__ cntm,
                                             uint2* __restrict__ bkth,
                                             uint2* __restrict__ bktm) {
    __shared__ uint2 lbkt[CAP_M];
    __shared__ u32 lcnt;
    const int blk = blockIdx.x;          // 2000 = 16 b x 125 panel-groups
    const int b   = blk / 125;
    const int mg  = blk % 125;
    const int t   = threadIdx.x;
    const int hw  = t << 2;
    if (t == 0) lcnt = 0;
    __syncthreads();

    float4 Z4 = *(const float4*)&Z[(b << 10) + hw];
    const float4 rZ = {1.f / Z4.x, 1.f / Z4.y, 1.f / Z4.z, 1.f / Z4.w};
    const size_t pb = ((size_t)(b * MEM_DIM + mg * 16) << 10) + hw;

#pragma unroll
    for (int i = 0; i < 16; ++i) {
        const int m = mg * 16 + i;
        float4 e = *(const float4*)&att[pb + ((size_t)i << 10)];
        float aa[4] = {e.x * rZ.x, e.y * rZ.y, e.z * rZ.z, e.w * rZ.w};
#pragma unroll
        for (int c = 0; c < 4; ++c) {
            const float d = aa[c] - LAMBDA;
            if (d > 0.f) {
                const float sv = d * aa[c] / (d + HS_EPS);   // == fmax(d,0)*a/(|d|+eps)
                const int hwc = hw + c;
                atomicAdd(&dD[(b << 10) + hwc], sv);
                const int ch = (b << 6) + (hwc >> 4);
                u32 ih = atomicAdd(&cnth[ch], 1u);
                if (ih < (u32)CAP_H)
                    bkth[ch * CAP_H + ih] =
                        make_uint2((u32)m | ((u32)(hwc & 15) << 16), __float_as_uint(sv));
                u32 im = atomicAdd(&lcnt, 1u);
                if (im < (u32)CAP_M)
                    lbkt[im] = make_uint2((u32)hwc | ((u32)(m & 15) << 16),
                                          __float_as_uint(sv));
            }
        }
    }
    __syncthreads();
    const u32 n = lcnt;
    if (t == 0) cntm[blk] = n;
    if (t < n && t < (u32)CAP_M) bktm[blk * CAP_M + t] = lbkt[t];
}

// ---------------------------------------------------------------------------
// Kernel 4: att production, panel-contiguous: zero-fill + survivor scatter.
// Overflow fallback: dense recompute from still-intact E of this panel.
// ---------------------------------------------------------------------------
__global__ __launch_bounds__(256) void k_att(float* __restrict__ att,
                                             const float* __restrict__ Z,
                                             const float* __restrict__ dD,
                                             const u32* __restrict__ cntm,
                                             const uint2* __restrict__ bktm) {
    const int blk = blockIdx.x;          // 2000
    const int b   = blk / 125;
    const int mg  = blk % 125;
    const int t   = threadIdx.x;
    const size_t pb = (size_t)(b * MEM_DIM + mg * 16) << 10;
    const u32 n_raw = cntm[blk];

    if (n_raw <= (u32)CAP_M) {
        float4* p4 = (float4*)&att[pb];
        const float4 z4 = {0.f, 0.f, 0.f, 0.f};
        for (int i = t; i < 4096; i += 256) p4[i] = z4;
        __syncthreads();
        const int n = (int)n_raw;
        for (int i = t; i < n; i += 256) {
            uint2 e = bktm[blk * CAP_M + i];
            const int hw = e.x & 0xFFFF;
            const int mi = e.x >> 16;
            const float rd = 1.f / fmaxf(dD[(b << 10) + hw], HS_EPS);
            att[pb + ((size_t)mi << 10) + hw] = __uint_as_float(e.y) * rd;
        }
    } else {
#pragma unroll
        for (int c = 0; c < 4; ++c) {
            const int hw = t + (c << 8);
            const float rz = 1.f / Z[(b << 10) + hw];
            const float rd = 1.f / fmaxf(dD[(b << 10) + hw], HS_EPS);
            for (int mi = 0; mi < 16; ++mi) {
                float e = att[pb + ((size_t)mi << 10) + hw];
                float a = e * rz, d = a - LAMBDA;
                att[pb + ((size_t)mi << 10) + hw] =
                    fmaxf(d, 0.f) * a / (fabsf(d) + HS_EPS) * rd;
            }
        }
    }
}

// ---------------------------------------------------------------------------
// Kernel 5: y from hw-chunk survivor buckets (rD at consumption).
// Overflow fallback: dense scan of FINAL att (k_att ran before).
// ---------------------------------------------------------------------------
__global__ __launch_bounds__(256) void k_y(const float* __restrict__ W,
                                           const u32* __restrict__ cnth,
                                           const uint2* __restrict__ bkth,
                                           const float* __restrict__ dD,
                                           const float* __restrict__ att,
                                           float* __restrict__ y) {
    __shared__ float ylds[16][257];
    __shared__ float rDsh[16];
    const int ch  = blockIdx.x;           // 1024
    const int b   = ch >> 6;
    const int hw0 = (ch & 63) << 4;
    const int t   = threadIdx.x;

    for (int i = t; i < 16 * 257; i += 256) ((float*)ylds)[i] = 0.f;
    if (t < 16) rDsh[t] = 1.f / fmaxf(dD[(b << 10) + hw0 + t], HS_EPS);
    __syncthreads();

    const u32 n_raw = cnth[ch];
    if (n_raw <= (u32)CAP_H) {
        const int n = (int)n_raw;
        for (int i = 0; i < n; ++i) {
            uint2 e = bkth[ch * CAP_H + i];
            const int m  = e.x & 0xFFFF;
            const int r4 = e.x >> 16;
            const float v = __uint_as_float(e.y) * rDsh[r4];
            ylds[r4][t] += v * W[(m << 8) + t];
        }
    } else {
        const int r  = t & 15;
        const int mo = t >> 4;
        for (int m = mo; m < MEM_DIM; m += 16) {
            float a = att[((size_t)(b * MEM_DIM + m) << 10) + hw0 + r];
            if (a != 0.f) {
                for (int c = 0; c < 256; ++c)
                    atomicAdd(&ylds[r][c], a * W[(m << 8) + c]);
            }
        }
    }
    __syncthreads();

#pragma unroll
    for (int it = 0; it < 16; ++it) {
        const int cc = (it << 4) + (t >> 4);
        const int r  = t & 15;
        y[(((b << 8) + cc) << 10) + hw0 + r] = ylds[r][cc];
    }
}

// ---------------------------------------------------------------------------
extern "C" void kernel_launch(void* const* d_in, const int* in_sizes, int n_in,
                              void* d_out, int out_size, void* d_ws, size_t ws_size,
                              hipStream_t stream) {
    const float* x = (const float*)d_in[0];
    const float* W = (const float*)d_in[1];
    float* out = (float*)d_out;
    float* y   = out;
    float* att = out + (size_t)Y_ELEMS;
    float* wsf = (float*)d_ws;
    u16*   wsp  = (u16*)d_ws;                 // 2 MB, dead after k_scores_mfma
    float* Z    = wsf + WS_Z;                 // reuses wsp region
    float* dD   = wsf + WS_DD;                // reuses wsp region
    u32*   cnth = (u32*)(wsf + WS_CNTH);      // reuses wsp region
    u32*   cntm = (u32*)(wsf + WS_CNTM);      // reuses wsp region
    uint2* bkth = (uint2*)(wsf + WS_BKTH);    // reuses wsp region
    uint2* bktm = (uint2*)(wsf + WS_BKTM);    // reuses wsp tail + dead zp
    float* zp   = wsf + WS_ZP;                // dead after k_zsum
    u16*   xs   = (u16*)y;                    // 16.8 MB staging in y region
                                              // (consumed before k_y writes y)

    k_split      <<<6144, 256, 0, stream>>>(x, W, xs, wsp);
    k_scores_mfma<<<2048, 256, 0, stream>>>(xs, wsp, att, zp);
    k_zsum       <<<64,   256, 0, stream>>>(zp, Z, dD, cnth, cntm);
    k_pvD        <<<2000, 256, 0, stream>>>(att, Z, dD, cnth, cntm, bkth, bktm);
    k_att        <<<2000, 256, 0, stream>>>(att, Z, dD, cntm, bktm);
    k_y          <<<1024, 256, 0, stream>>>(W, cnth, bkth, dD, att, y);
}

// Round 17
// 142.184 us; speedup vs baseline: 1.0686x; 1.0227x over previous
//
#include <hip/hip_runtime.h>
#include <cfloat>
#include <cmath>

#define MEM_DIM 2000
#define FEA     256
#define LAMBDA  0.0025f
#define HS_EPS  1e-12f

typedef unsigned short u16;
typedef unsigned int   u32;
typedef _Float16 f16x8  __attribute__((ext_vector_type(8)));
typedef float    f32x16 __attribute__((ext_vector_type(16)));

static const int Y_ELEMS = 16 * 256 * 1024;   // y output elements

// workspace layout (float offsets), total 783616 floats < 3.0 MB:
//   [0 .. 524287]      : wsp u16[2][2048][256] (2 MB) while scores runs
//   [524288 .. 786431] : zp [16][16384] (1 MB) until k_zsum consumes it
//   AFTER those phases the regions are reused:
#define WS_Z     0        //  Z    [16384] full row sums
#define WS_DD    16384    //  dD   [16384] L1 denominators (atomic, survivor-only)
#define WS_CNTH  32768    //  cnth [1024] hw-chunk counters (u32, pad 2048)
#define WS_CNTM  34816    //  cntm [2000] m-panel counters (u32, pad 2048)
#define WS_BKTH  36864    //  bkth [1024][224] uint2 -> ends 495616
#define WS_BKTM  495616   //  bktm [2000][72]  uint2 -> ends 783616 (annexes dead zp)
#define WS_ZP    524288   //  zp (dead after k_zsum)
#define CAP_H 224
#define CAP_M 72

// ---------------------------------------------------------------------------
// Kernel A+B merged: split x -> xs planes; split W -> wsp planes.
// ---------------------------------------------------------------------------
__global__ __launch_bounds__(256) void k_split(const float* __restrict__ x,
                                               const float* __restrict__ W,
                                               u16* __restrict__ xs,
                                               u16* __restrict__ wsp) {
    __shared__ float tl[32][33];
    const int blk = blockIdx.x;
    if (blk < 4096) {
        const int b   = blk >> 8;
        const int ct  = (blk >> 5) & 7;
        const int ht  = blk & 31;
        const int tx  = threadIdx.x & 31, ty = threadIdx.x >> 5;
#pragma unroll
        for (int i = 0; i < 4; ++i)
            tl[ty + 8 * i][tx] =
                x[(((b << 8) + (ct << 5) + ty + (i << 3)) << 10) + (ht << 5) + tx];
        __syncthreads();
#pragma unroll
        for (int i = 0; i < 4; ++i) {
            float v = tl[tx][ty + 8 * i];
            _Float16 a  = (_Float16)v;
            _Float16 bq = (_Float16)((v - (float)a) * 256.0f);
            const int hw = (ht << 5) + ty + (i << 3);
            const int c  = (ct << 5) + tx;
            const size_t o = (((size_t)(b << 10) + hw) << 8) + c;
            xs[o]           = *(u16*)&a;
            xs[4194304 + o] = *(u16*)&bq;
        }
    } else {
        const int m = blk - 4096;             // 0..2047
        const int c = threadIdx.x;
        float v = (m < MEM_DIM) ? W[(m << 8) + c] : 0.f;
        _Float16 a  = (_Float16)v;
        _Float16 bq = (_Float16)((v - (float)a) * 256.0f);
        wsp[(m << 8) + c]          = *(u16*)&a;
        wsp[524288 + (m << 8) + c] = *(u16*)&bq;
    }
}

// ---------------------------------------------------------------------------
// Kernel 1: z = x.W^T via mfma_f32_32x32x16_f16, 2-split (3 passes, dual acc).
// r13/r16 structure with counted-vmcnt pipeline (T4), PROPERLY FENCED:
//   STAGE(kt+1) -> sched_barrier(0) -> s_waitcnt vmcnt(8) -> sched_barrier(0)
//   -> s_barrier (builtin) -> COMPUTE(kt) -> sched_barrier(0) -> s_barrier.
// sched_barrier(0) after STAGE pins all 8 DMA issues ABOVE the vmcnt asm
// (r15's race: scheduler sank DMAs below the asm waitcnt so vmcnt(8) did not
// cover tile kt). Builtin s_barrier is compiler-aware. MFMA order unchanged
// -> E bit-identical to rounds 11/13/16.
// ---------------------------------------------------------------------------
__global__ __launch_bounds__(256) void k_scores_mfma(
    const u16* __restrict__ xs, const u16* __restrict__ wsp,
    float* __restrict__ S, float* __restrict__ zp) {
    __shared__ u16 lds[32768];   // 64 KB = 2 x 32 KB buffers
    const int t    = threadIdx.x;
    const int lane = t & 63;
    const int w    = t >> 6;
    const int wr   = w >> 1, wc = w & 1;
    const int lr   = lane & 31, lg = lane >> 5;

    const int bx  = blockIdx.x;
    const int wg  = ((bx & 7) << 8) | (bx >> 3);   // XCD swizzle (2048 = 8*256)
    const int m0t = wg & 15;
    const int rt  = wg >> 4;
    const int m0  = m0t << 7;
    const int b   = rt >> 3;
    const int hw0 = (rt & 7) << 7;

    const u16* gsrc[8];
#pragma unroll
    for (int i = 0; i < 8; ++i) {
        const int s = (i << 8) + t;
        const int tile = s >> 9;
        const int u = s & 511;
        const int r = u >> 2;
        const int cl = (u & 3) ^ ((r >> 1) & 3);
        if (tile < 2)
            gsrc[i] = xs + tile * 4194304 + (((b << 10) + hw0 + r) << 8) + (cl << 3);
        else
            gsrc[i] = wsp + ((tile - 2) << 19) + ((m0 + r) << 8) + (cl << 3);
    }

    f32x16 acc1[2][2], acc2[2][2];
#pragma unroll
    for (int i = 0; i < 2; ++i)
#pragma unroll
        for (int j = 0; j < 2; ++j)
#pragma unroll
            for (int e = 0; e < 16; ++e) { acc1[i][j][e] = 0.f; acc2[i][j][e] = 0.f; }

    #define STAGE(kt, bufb)                                                          \
        {                                                                            \
            _Pragma("unroll")                                                        \
            for (int i = 0; i < 8; ++i) {                                            \
                const int s = (i << 8) + t;                                          \
                __builtin_amdgcn_global_load_lds(                                    \
                    (const __attribute__((address_space(1))) unsigned int*)(gsrc[i] + ((kt) << 5)), \
                    (__attribute__((address_space(3))) unsigned int*)&lds[(bufb) + (s << 3)],       \
                    16, 0, 0);                                                       \
            }                                                                        \
        }

    #define COMPUTE(bufb)                                                            \
        {                                                                            \
            _Pragma("unroll")                                                        \
            for (int ks = 0; ks < 2; ++ks) {                                         \
                f16x8 a0[2], a1[2], b0[2], b1[2];                                    \
                _Pragma("unroll")                                                    \
                for (int ri = 0; ri < 2; ++ri) {                                     \
                    const int R  = (wr << 6) + (ri << 5) + lr;                       \
                    const int pc = ((ks << 1) + lg) ^ ((R >> 1) & 3);                \
                    a0[ri] = *(const f16x8*)&lds[(bufb) +        (R << 5) + (pc << 3)]; \
                    a1[ri] = *(const f16x8*)&lds[(bufb) + 4096 + (R << 5) + (pc << 3)]; \
                }                                                                    \
                _Pragma("unroll")                                                    \
                for (int mi = 0; mi < 2; ++mi) {                                     \
                    const int M  = (wc << 6) + (mi << 5) + lr;                       \
                    const int pc = ((ks << 1) + lg) ^ ((M >> 1) & 3);                \
                    b0[mi] = *(const f16x8*)&lds[(bufb) +  8192 + (M << 5) + (pc << 3)]; \
                    b1[mi] = *(const f16x8*)&lds[(bufb) + 12288 + (M << 5) + (pc << 3)]; \
                }                                                                    \
                _Pragma("unroll")                                                    \
                for (int ri = 0; ri < 2; ++ri)                                       \
                    _Pragma("unroll")                                                \
                    for (int mi = 0; mi < 2; ++mi) {                                 \
                        acc2[ri][mi] = __builtin_amdgcn_mfma_f32_32x32x16_f16(a0[ri], b1[mi], acc2[ri][mi], 0, 0, 0); \
                        acc2[ri][mi] = __builtin_amdgcn_mfma_f32_32x32x16_f16(a1[ri], b0[mi], acc2[ri][mi], 0, 0, 0); \
                        acc1[ri][mi] = __builtin_amdgcn_mfma_f32_32x32x16_f16(a0[ri], b0[mi], acc1[ri][mi], 0, 0, 0); \
                    }                                                                \
            }                                                                        \
        }

    STAGE(0, 0);
#pragma unroll
    for (int kt = 0; kt < 8; ++kt) {
        if (kt < 7) STAGE(kt + 1, ((kt + 1) & 1) << 14);   // prefetch in flight
        __builtin_amdgcn_sched_barrier(0);   // pin: all DMA issues above waitcnt
        if (kt < 7) {
            asm volatile("s_waitcnt vmcnt(8)" ::: "memory");  // tile kt landed
        } else {
            asm volatile("s_waitcnt vmcnt(0)" ::: "memory");  // final drain
        }
        __builtin_amdgcn_sched_barrier(0);
        __builtin_amdgcn_s_barrier();        // A: tile kt visible to all waves
        __builtin_amdgcn_sched_barrier(0);
        COMPUTE((kt & 1) << 14);
        __builtin_amdgcn_sched_barrier(0);   // pin ds_reads above barrier B
        __builtin_amdgcn_s_barrier();        // B: buffer free for overwrite
        __builtin_amdgcn_sched_barrier(0);
    }
    #undef STAGE
    #undef COMPUTE

    float* zf = (float*)lds;

    float rs[2][16];
#pragma unroll
    for (int ri = 0; ri < 2; ++ri)
#pragma unroll
        for (int q = 0; q < 16; ++q) rs[ri][q] = 0.f;

#pragma unroll
    for (int ri = 0; ri < 2; ++ri)
#pragma unroll
        for (int mi = 0; mi < 2; ++mi) {
            const int m = m0 + (wc << 6) + (mi << 5) + lr;
            const bool valid = (m < MEM_DIM);
            float e[16];
#pragma unroll
            for (int q = 0; q < 16; ++q) {
                float z = acc1[ri][mi][q] + acc2[ri][mi][q] * 0.00390625f;
                e[q] = valid ? expf(z) : 0.f;
                rs[ri][q] += e[q];
            }
            if (valid) {
                const size_t pb = ((size_t)(b * MEM_DIM + m) << 10) + hw0
                                + (wr << 6) + (ri << 5) + (lg << 2);
#pragma unroll
                for (int q4 = 0; q4 < 4; ++q4) {
                    float4 v = {e[4 * q4], e[4 * q4 + 1], e[4 * q4 + 2], e[4 * q4 + 3]};
                    *(float4*)&S[pb + (q4 << 3)] = v;
                }
            }
        }

#pragma unroll
    for (int ri = 0; ri < 2; ++ri)
#pragma unroll
        for (int q = 0; q < 16; ++q) {
            float v = rs[ri][q];
            v += __shfl_xor(v, 1);
            v += __shfl_xor(v, 2);
            v += __shfl_xor(v, 4);
            v += __shfl_xor(v, 8);
            v += __shfl_xor(v, 16);
            rs[ri][q] = v;
        }
    if (lr == 0) {
#pragma unroll
        for (int ri = 0; ri < 2; ++ri)
#pragma unroll
            for (int q = 0; q < 16; ++q) {
                const int row = (wr << 6) + (ri << 5) + (q & 3) + ((q >> 2) << 3) + (lg << 2);
                zf[(wc << 7) + row] = rs[ri][q];
            }
    }
    __syncthreads();
    if (t < 128)
        zp[m0t * 16384 + (b << 10) + hw0 + t] = zf[t] + zf[128 + t];
}

// ---------------------------------------------------------------------------
// Kernel 2: Z = sum of 16 zp planes; zero dD and both counter arrays.
// ---------------------------------------------------------------------------
__global__ __launch_bounds__(256) void k_zsum(const float* __restrict__ zp,
                                              float* __restrict__ Z,
                                              float* __restrict__ dD,
                                              u32* __restrict__ cnth,
                                              u32* __restrict__ cntm) {
    const int i = blockIdx.x * 256 + threadIdx.x;   // 16384
    float z = 0.f;
#pragma unroll
    for (int mt = 0; mt < 16; ++mt) z += zp[mt * 16384 + i];
    Z[i] = z;
    dD[i] = 0.f;
    if (i < 1024) cnth[i] = 0;
    if (i < 2048) cntm[i] = 0;
}

// ---------------------------------------------------------------------------
// Kernel 3: single dense E-consumer (round-13-proven). Survivors (d>0):
// survivor-only dD atomics, global-atomic bkth append, LDS-staged bktm.
// ---------------------------------------------------------------------------
__global__ __launch_bounds__(256) void k_pvD(const float* __restrict__ att,
                                             const float* __restrict__ Z,
                                             float* __restrict__ dD,
                                             u32* __restrict__ cnth,
                                             u32* __restrict__ cntm,
                                             uint2* __restrict__ bkth,
                                             uint2* __restrict__ bktm) {
    __shared__ uint2 lbkt[CAP_M];
    __shared__ u32 lcnt;
    const int blk = blockIdx.x;          // 2000 = 16 b x 125 panel-groups
    const int b   = blk / 125;
    const int mg  = blk % 125;
    const int t   = threadIdx.x;
    const int hw  = t << 2;
    if (t == 0) lcnt = 0;
    __syncthreads();

    float4 Z4 = *(const float4*)&Z[(b << 10) + hw];
    const float4 rZ = {1.f / Z4.x, 1.f / Z4.y, 1.f / Z4.z, 1.f / Z4.w};
    const size_t pb = ((size_t)(b * MEM_DIM + mg * 16) << 10) + hw;

#pragma unroll
    for (int i = 0; i < 16; ++i) {
        const int m = mg * 16 + i;
        float4 e = *(const float4*)&att[pb + ((size_t)i << 10)];
        float aa[4] = {e.x * rZ.x, e.y * rZ.y, e.z * rZ.z, e.w * rZ.w};
#pragma unroll
        for (int c = 0; c < 4; ++c) {
            const float d = aa[c] - LAMBDA;
            if (d > 0.f) {
                const float sv = d * aa[c] / (d + HS_EPS);   // == fmax(d,0)*a/(|d|+eps)
                const int hwc = hw + c;
                atomicAdd(&dD[(b << 10) + hwc], sv);
                const int ch = (b << 6) + (hwc >> 4);
                u32 ih = atomicAdd(&cnth[ch], 1u);
                if (ih < (u32)CAP_H)
                    bkth[ch * CAP_H + ih] =
                        make_uint2((u32)m | ((u32)(hwc & 15) << 16), __float_as_uint(sv));
                u32 im = atomicAdd(&lcnt, 1u);
                if (im < (u32)CAP_M)
                    lbkt[im] = make_uint2((u32)hwc | ((u32)(m & 15) << 16),
                                          __float_as_uint(sv));
            }
        }
    }
    __syncthreads();
    const u32 n = lcnt;
    if (t == 0) cntm[blk] = n;
    if (t < n && t < (u32)CAP_M) bktm[blk * CAP_M + t] = lbkt[t];
}

// ---------------------------------------------------------------------------
// Kernel 4: att production, panel-contiguous: zero-fill + survivor scatter.
// Overflow fallback: dense recompute from still-intact E of this panel.
// ---------------------------------------------------------------------------
__global__ __launch_bounds__(256) void k_att(float* __restrict__ att,
                                             const float* __restrict__ Z,
                                             const float* __restrict__ dD,
                                             const u32* __restrict__ cntm,
                                             const uint2* __restrict__ bktm) {
    const int blk = blockIdx.x;          // 2000
    const int b   = blk / 125;
    const int mg  = blk % 125;
    const int t   = threadIdx.x;
    const size_t pb = (size_t)(b * MEM_DIM + mg * 16) << 10;
    const u32 n_raw = cntm[blk];

    if (n_raw <= (u32)CAP_M) {
        float4* p4 = (float4*)&att[pb];
        const float4 z4 = {0.f, 0.f, 0.f, 0.f};
        for (int i = t; i < 4096; i += 256) p4[i] = z4;
        __syncthreads();
        const int n = (int)n_raw;
        for (int i = t; i < n; i += 256) {
            uint2 e = bktm[blk * CAP_M + i];
            const int hw = e.x & 0xFFFF;
            const int mi = e.x >> 16;
            const float rd = 1.f / fmaxf(dD[(b << 10) + hw], HS_EPS);
            att[pb + ((size_t)mi << 10) + hw] = __uint_as_float(e.y) * rd;
        }
    } else {
#pragma unroll
        for (int c = 0; c < 4; ++c) {
            const int hw = t + (c << 8);
            const float rz = 1.f / Z[(b << 10) + hw];
            const float rd = 1.f / fmaxf(dD[(b << 10) + hw], HS_EPS);
            for (int mi = 0; mi < 16; ++mi) {
                float e = att[pb + ((size_t)mi << 10) + hw];
                float a = e * rz, d = a - LAMBDA;
                att[pb + ((size_t)mi << 10) + hw] =
                    fmaxf(d, 0.f) * a / (fabsf(d) + HS_EPS) * rd;
            }
        }
    }
}

// ---------------------------------------------------------------------------
// Kernel 5: y from hw-chunk survivor buckets (rD at consumption).
// Overflow fallback: dense scan of FINAL att (k_att ran before).
// ---------------------------------------------------------------------------
__global__ __launch_bounds__(256) void k_y(const float* __restrict__ W,
                                           const u32* __restrict__ cnth,
                                           const uint2* __restrict__ bkth,
                                           const float* __restrict__ dD,
                                           const float* __restrict__ att,
                                           float* __restrict__ y) {
    __shared__ float ylds[16][257];
    __shared__ float rDsh[16];
    const int ch  = blockIdx.x;           // 1024
    const int b   = ch >> 6;
    const int hw0 = (ch & 63) << 4;
    const int t   = threadIdx.x;

    for (int i = t; i < 16 * 257; i += 256) ((float*)ylds)[i] = 0.f;
    if (t < 16) rDsh[t] = 1.f / fmaxf(dD[(b << 10) + hw0 + t], HS_EPS);
    __syncthreads();

    const u32 n_raw = cnth[ch];
    if (n_raw <= (u32)CAP_H) {
        const int n = (int)n_raw;
        for (int i = 0; i < n; ++i) {
            uint2 e = bkth[ch * CAP_H + i];
            const int m  = e.x & 0xFFFF;
            const int r4 = e.x >> 16;
            const float v = __uint_as_float(e.y) * rDsh[r4];
            ylds[r4][t] += v * W[(m << 8) + t];
        }
    } else {
        const int r  = t & 15;
        const int mo = t >> 4;
        for (int m = mo; m < MEM_DIM; m += 16) {
            float a = att[((size_t)(b * MEM_DIM + m) << 10) + hw0 + r];
            if (a != 0.f) {
                for (int c = 0; c < 256; ++c)
                    atomicAdd(&ylds[r][c], a * W[(m << 8) + c]);
            }
        }
    }
    __syncthreads();

#pragma unroll
    for (int it = 0; it < 16; ++it) {
        const int cc = (it << 4) + (t >> 4);
        const int r  = t & 15;
        y[(((b << 8) + cc) << 10) + hw0 + r] = ylds[r][cc];
    }
}

// ---------------------------------------------------------------------------
extern "C" void kernel_launch(void* const* d_in, const int* in_sizes, int n_in,
                              void* d_out, int out_size, void* d_ws, size_t ws_size,
                              hipStream_t stream) {
    const float* x = (const float*)d_in[0];
    const float* W = (const float*)d_in[1];
    float* out = (float*)d_out;
    float* y   = out;
    float* att = out + (size_t)Y_ELEMS;
    float* wsf = (float*)d_ws;
    u16*   wsp  = (u16*)d_ws;                 // 2 MB, dead after k_scores_mfma
    float* Z    = wsf + WS_Z;                 // reuses wsp region
    float* dD   = wsf + WS_DD;                // reuses wsp region
    u32*   cnth = (u32*)(wsf + WS_CNTH);      // reuses wsp region
    u32*   cntm = (u32*)(wsf + WS_CNTM);      // reuses wsp region
    uint2* bkth = (uint2*)(wsf + WS_BKTH);    // reuses wsp region
    uint2* bktm = (uint2*)(wsf + WS_BKTM);    // reuses wsp tail + dead zp
    float* zp   = wsf + WS_ZP;                // dead after k_zsum
    u16*   xs   = (u16*)y;                    // 16.8 MB staging in y region
                                              // (consumed before k_y writes y)

    k_split      <<<6144, 256, 0, stream>>>(x, W, xs, wsp);
    k_scores_mfma<<<2048, 256, 0, stream>>>(xs, wsp, att, zp);
    k_zsum       <<<64,   256, 0, stream>>>(zp, Z, dD, cnth, cntm);
    k_pvD        <<<2000, 256, 0, stream>>>(att, Z, dD, cnth, cntm, bkth, bktm);
    k_att        <<<2000, 256, 0, stream>>>(att, Z, dD, cntm, bktm);
    k_y          <<<1024, 256, 0, stream>>>(W, cnth, bkth, dD, att, y);
}